// Round 1
// 139.336 us; speedup vs baseline: 1.2956x; 1.2956x over previous
//
#include <hip/hip_runtime.h>
#include <hip/hip_bf16.h>

#define N_ROWS 8192
#define DIM    128
#define TWO_N  16384
#define CSPLIT 32
#define COLS_PER_BLOCK (TWO_N / CSPLIT)   // 512
#define CT 32                             // cols per LDS tile
#define NT (COLS_PER_BLOCK / CT)          // 16 tiles
#define EXP_TWO 7.38905609893065f
// sqrt(2 * log2(e)): folding exp(2*dot) == exp2(SCALE^2 * dot) into the operands
#define H_SCALE 1.6986436f

typedef __attribute__((ext_vector_type(8))) short short8;
typedef __attribute__((ext_vector_type(4))) float float4v;

__device__ inline void async_copy16(const void* g, void* l) {
  __builtin_amdgcn_global_load_lds(
      (const __attribute__((address_space(1))) void*)g,
      (__attribute__((address_space(3))) void*)l, 16, 0, 0);
}

__device__ inline float fast_exp2(float x) {
#if __has_builtin(__builtin_amdgcn_exp2f)
  return __builtin_amdgcn_exp2f(x);
#else
  return exp2f(x);
#endif
}

// ---------------------------------------------------------------------------
// Kernel 1: L2-normalize rows of h1,h2 (fp32), write bf16 H = [h1n; h2n]
// scaled by sqrt(2*log2 e) so the GEMM accumulator is already the exp2 arg.
// Also writes exact fp32 pos-dot per row (unscaled) and zeroes rowsum
// (replaces the hipMemsetAsync dispatch; stream-ordered before ntx_main).
// One wave per row; block = 4 waves.
// ---------------------------------------------------------------------------
__global__ __launch_bounds__(256) void norm_kernel(
    const float* __restrict__ h1, const float* __restrict__ h2,
    __hip_bfloat16* __restrict__ Hb, float* __restrict__ posdot,
    float* __restrict__ rowsum) {
  // zero rowsum[16384]: 2048 blocks x 8 entries
  if (threadIdx.x < 8) rowsum[blockIdx.x * 8 + threadIdx.x] = 0.0f;

  int lane = threadIdx.x & 63;
  int w    = threadIdx.x >> 6;
  int row  = blockIdx.x * 4 + w;                  // 0..8191

  const float2* p1 = (const float2*)(h1 + (size_t)row * DIM);
  const float2* p2 = (const float2*)(h2 + (size_t)row * DIM);
  float2 v1 = p1[lane];
  float2 v2 = p2[lane];

  float ss1 = v1.x * v1.x + v1.y * v1.y;
  float ss2 = v2.x * v2.x + v2.y * v2.y;
  #pragma unroll
  for (int m = 32; m; m >>= 1) {
    ss1 += __shfl_xor(ss1, m);
    ss2 += __shfl_xor(ss2, m);
  }
  float inv1 = 1.0f / fmaxf(sqrtf(ss1), 1e-12f);
  float inv2 = 1.0f / fmaxf(sqrtf(ss2), 1e-12f);

  float ax = v1.x * inv1, ay = v1.y * inv1;
  float bx = v2.x * inv2, by = v2.y * inv2;

  float pd = ax * bx + ay * by;       // exact fp32 posdot (unscaled)
  #pragma unroll
  for (int m = 32; m; m >>= 1) pd += __shfl_xor(pd, m);

  __hip_bfloat162* o1 = (__hip_bfloat162*)(Hb + (size_t)row * DIM);
  __hip_bfloat162* o2 = (__hip_bfloat162*)(Hb + (size_t)(row + N_ROWS) * DIM);
  __hip_bfloat162 t1, t2;
  t1.x = __float2bfloat16(ax * H_SCALE); t1.y = __float2bfloat16(ay * H_SCALE);
  t2.x = __float2bfloat16(bx * H_SCALE); t2.y = __float2bfloat16(by * H_SCALE);
  o1[lane] = t1;
  o2[lane] = t2;

  if (lane == 0) posdot[row] = pd;
}

// ---------------------------------------------------------------------------
// Kernel 2: row sums of exp2(H H^T) (H pre-scaled so this == exp(2*dot))
// without materializing the matrix.
// Block: 256 threads = 4 waves; each wave owns 64 rows (A in registers,
// K=128 entirely resident). B tiles (32 cols x 128 k) staged to LDS via
// global_load_lds in MFMA fragment order, so ds_read_b128 is lane-sequential.
// Grid: (64 row-stripes, 32 col-splits) = 2048 blocks -> full wave capacity.
// Partial row sums via atomicAdd.
// ---------------------------------------------------------------------------
__global__ __launch_bounds__(256, 2) void ntx_main(
    const __hip_bfloat16* __restrict__ Hb, float* __restrict__ rowsum) {
  __shared__ short smem[512 * 8];   // 8 KB: 512 chunks of 16 B
  const short* H = (const short*)Hb;

  int tid  = threadIdx.x;
  int lane = tid & 63;
  int w    = tid >> 6;
  int q    = lane >> 4;     // k-chunk selector within fragment
  int m    = lane & 15;     // row-within-subtile / col-within-subtile

  int rowbase = blockIdx.x * 256 + w * 64;
  int colbase = blockIdx.y * COLS_PER_BLOCK;

  // A fragments: 4 row-subtiles x 4 k-steps, held for the whole kernel.
  short8 a[4][4];
  #pragma unroll
  for (int r = 0; r < 4; ++r)
    #pragma unroll
    for (int s = 0; s < 4; ++s)
      a[r][s] = *(const short8*)(H + (size_t)(rowbase + r * 16 + m) * DIM + s * 32 + q * 8);

  float rowacc[4][4];
  #pragma unroll
  for (int r = 0; r < 4; ++r)
    #pragma unroll
    for (int i = 0; i < 4; ++i) rowacc[r][i] = 0.0f;

  for (int ct = 0; ct < NT; ++ct) {
    int j0 = colbase + ct * CT;
    // Stage B tile (32 rows of H x 128 k) in fragment order.
    #pragma unroll
    for (int rr = 0; rr < 2; ++rr) {
      int i   = rr * 256 + tid;          // chunk index 0..511
      int c   = i >> 8;                  // col-subtile
      int s   = (i >> 6) & 3;            // k-step
      int l15 = i & 15;                  // lane&15 -> B row within subtile
      int lq  = (i >> 4) & 3;            // lane>>4 -> k chunk
      const short* g = H + (size_t)(j0 + c * 16 + l15) * DIM + s * 32 + lq * 8;
      async_copy16(g, (void*)&smem[i * 8]);
    }
    __syncthreads();   // compiler emits s_waitcnt vmcnt(0) before s_barrier

    #pragma unroll
    for (int c = 0; c < 2; ++c) {
      short8 b[4];
      #pragma unroll
      for (int s = 0; s < 4; ++s)
        b[s] = *(const short8*)&smem[(c * 256 + s * 64 + lane) * 8];
      #pragma unroll
      for (int r = 0; r < 4; ++r) {
        float4v acc = {0.f, 0.f, 0.f, 0.f};
        #pragma unroll
        for (int s = 0; s < 4; ++s)
          acc = __builtin_amdgcn_mfma_f32_16x16x32_bf16(a[r][s], b[s], acc, 0, 0, 0);
        #pragma unroll
        for (int i = 0; i < 4; ++i)
          rowacc[r][i] += fast_exp2(acc[i]);   // acc already = 2*log2e*dot
      }
    }
    __syncthreads();
  }

  // Reduce across the 16 column-lanes (lane&15) holding the same rows.
  #pragma unroll
  for (int r = 0; r < 4; ++r)
    #pragma unroll
    for (int i = 0; i < 4; ++i) {
      float v = rowacc[r][i];
      v += __shfl_xor(v, 1);
      v += __shfl_xor(v, 2);
      v += __shfl_xor(v, 4);
      v += __shfl_xor(v, 8);
      rowacc[r][i] = v;
    }
  if (m == 0) {
    #pragma unroll
    for (int r = 0; r < 4; ++r)
      #pragma unroll
      for (int i = 0; i < 4; ++i)
        atomicAdd(&rowsum[rowbase + r * 16 + q * 4 + i], rowacc[r][i]);
  }
}

// ---------------------------------------------------------------------------
// Kernel 3: loss = ( sum_i log(rowsum_i - e^2) - 4 * sum_i posdot_i ) / 2N
// 1024 threads (16 waves) to hide logf/load latency on the single block.
// ---------------------------------------------------------------------------
__global__ __launch_bounds__(1024) void finalize(
    const float* __restrict__ rowsum, const float* __restrict__ posdot,
    float* __restrict__ out) {
  __shared__ float red[32];
  int tid = threadIdx.x;
  float ld = 0.0f, pp = 0.0f;
  for (int i = tid; i < TWO_N; i += 1024) ld += logf(rowsum[i] - EXP_TWO);
  for (int i = tid; i < N_ROWS; i += 1024) pp += posdot[i];
  #pragma unroll
  for (int m = 32; m; m >>= 1) {
    ld += __shfl_xor(ld, m);
    pp += __shfl_xor(pp, m);
  }
  if ((tid & 63) == 0) {
    red[tid >> 6] = ld;
    red[16 + (tid >> 6)] = pp;
  }
  __syncthreads();
  if (tid == 0) {
    float tl = 0.0f, tp = 0.0f;
    #pragma unroll
    for (int i = 0; i < 16; ++i) { tl += red[i]; tp += red[16 + i]; }
    *out = (tl - 4.0f * tp) / (float)TWO_N;
  }
}

extern "C" void kernel_launch(void* const* d_in, const int* in_sizes, int n_in,
                              void* d_out, int out_size, void* d_ws, size_t ws_size,
                              hipStream_t stream) {
  const float* h1 = (const float*)d_in[0];
  const float* h2 = (const float*)d_in[1];
  char* ws = (char*)d_ws;

  __hip_bfloat16* Hb = (__hip_bfloat16*)ws;                       // 4 MB
  float* rowsum      = (float*)(ws + 4194304);                    // 64 KB
  float* posdot      = (float*)(ws + 4194304 + 65536);            // 32 KB
  float* out         = (float*)d_out;

  norm_kernel<<<N_ROWS / 4, 256, 0, stream>>>(h1, h2, Hb, posdot, rowsum);
  ntx_main<<<dim3(TWO_N / 256, CSPLIT), 256, 0, stream>>>(Hb, rowsum);
  finalize<<<1, 1024, 0, stream>>>(rowsum, posdot, out);
}

// Round 2
// 135.806 us; speedup vs baseline: 1.3293x; 1.0260x over previous
//
#include <hip/hip_runtime.h>
#include <hip/hip_bf16.h>

#define N_ROWS 8192
#define DIM    128
#define TWO_N  16384
#define CSPLIT 32
#define COLS_PER_BLOCK (TWO_N / CSPLIT)   // 512
#define CT 32                             // cols per LDS tile
#define NT (COLS_PER_BLOCK / CT)          // 16 tiles
#define EXP_TWO 7.38905609893065f
// sqrt(2 * log2(e)): folding exp(2*dot) == exp2(SCALE^2 * dot) into the operands
#define H_SCALE 1.6986436f

typedef __attribute__((ext_vector_type(8))) short short8;
typedef __attribute__((ext_vector_type(4))) float float4v;

__device__ inline void async_copy16(const void* g, void* l) {
  __builtin_amdgcn_global_load_lds(
      (const __attribute__((address_space(1))) void*)g,
      (__attribute__((address_space(3))) void*)l, 16, 0, 0);
}

__device__ inline float fast_exp2(float x) {
#if __has_builtin(__builtin_amdgcn_exp2f)
  return __builtin_amdgcn_exp2f(x);
#else
  return exp2f(x);
#endif
}

// ---------------------------------------------------------------------------
// Kernel 1: L2-normalize rows of h1,h2 (fp32), write bf16 H = [h1n; h2n]
// scaled by sqrt(2*log2 e) so the GEMM accumulator is already the exp2 arg.
// Also writes exact fp32 pos-dot per row (unscaled) and zeroes rowsum.
// One wave per row; block = 4 waves.
// ---------------------------------------------------------------------------
__global__ __launch_bounds__(256) void norm_kernel(
    const float* __restrict__ h1, const float* __restrict__ h2,
    __hip_bfloat16* __restrict__ Hb, float* __restrict__ posdot,
    float* __restrict__ rowsum) {
  // zero rowsum[16384]: 2048 blocks x 8 entries
  if (threadIdx.x < 8) rowsum[blockIdx.x * 8 + threadIdx.x] = 0.0f;

  int lane = threadIdx.x & 63;
  int w    = threadIdx.x >> 6;
  int row  = blockIdx.x * 4 + w;                  // 0..8191

  const float2* p1 = (const float2*)(h1 + (size_t)row * DIM);
  const float2* p2 = (const float2*)(h2 + (size_t)row * DIM);
  float2 v1 = p1[lane];
  float2 v2 = p2[lane];

  float ss1 = v1.x * v1.x + v1.y * v1.y;
  float ss2 = v2.x * v2.x + v2.y * v2.y;
  #pragma unroll
  for (int m = 32; m; m >>= 1) {
    ss1 += __shfl_xor(ss1, m);
    ss2 += __shfl_xor(ss2, m);
  }
  float inv1 = 1.0f / fmaxf(sqrtf(ss1), 1e-12f);
  float inv2 = 1.0f / fmaxf(sqrtf(ss2), 1e-12f);

  float ax = v1.x * inv1, ay = v1.y * inv1;
  float bx = v2.x * inv2, by = v2.y * inv2;

  float pd = ax * bx + ay * by;       // exact fp32 posdot (unscaled)
  #pragma unroll
  for (int m = 32; m; m >>= 1) pd += __shfl_xor(pd, m);

  __hip_bfloat162* o1 = (__hip_bfloat162*)(Hb + (size_t)row * DIM);
  __hip_bfloat162* o2 = (__hip_bfloat162*)(Hb + (size_t)(row + N_ROWS) * DIM);
  __hip_bfloat162 t1, t2;
  t1.x = __float2bfloat16(ax * H_SCALE); t1.y = __float2bfloat16(ay * H_SCALE);
  t2.x = __float2bfloat16(bx * H_SCALE); t2.y = __float2bfloat16(by * H_SCALE);
  o1[lane] = t1;
  o2[lane] = t2;

  if (lane == 0) posdot[row] = pd;
}

// ---------------------------------------------------------------------------
// Kernel 2: row sums of exp2(H H^T) without materializing the matrix.
// Block: 256 threads = 4 waves; each wave owns 64 rows. A fragments are
// loaded ONCE and pinned in registers via a "+v" asm (the compiler was
// rematerializing them from global every tile at VGPR=60; this forces
// residency at ~4 waves/SIMD instead).
// B tiles (32 cols x 128 k) double-buffered in LDS via global_load_lds in
// MFMA fragment order; single __syncthreads per tile (prefetch of t+1 is
// issued before compute of t, so the vmcnt(0) drain is covered).
// Grid: (64 row-stripes, 32 col-splits). Partial row sums via atomicAdd.
// ---------------------------------------------------------------------------
__global__ __launch_bounds__(256, 2) void ntx_main(
    const __hip_bfloat16* __restrict__ Hb, float* __restrict__ rowsum) {
  __shared__ short smem[2 * 4096];   // 2 x 8KB: 2 x 512 chunks of 16 B
  const short* H = (const short*)Hb;

  int tid  = threadIdx.x;
  int lane = tid & 63;
  int w    = tid >> 6;
  int q    = lane >> 4;     // k-chunk selector within fragment
  int m    = lane & 15;     // row-within-subtile / col-within-subtile

  int rowbase = blockIdx.x * 256 + w * 64;
  int colbase = blockIdx.y * COLS_PER_BLOCK;

  // A fragments: 4 row-subtiles x 4 k-steps, held for the whole kernel.
  short8 a[4][4];
  #pragma unroll
  for (int r = 0; r < 4; ++r)
    #pragma unroll
    for (int s = 0; s < 4; ++s)
      a[r][s] = *(const short8*)(H + (size_t)(rowbase + r * 16 + m) * DIM + s * 32 + q * 8);
  // Pin A in registers: opaque volatile asm forbids remat/reload in the loop.
  #pragma unroll
  for (int r = 0; r < 4; ++r)
    #pragma unroll
    for (int s = 0; s < 4; ++s)
      asm volatile("" : "+v"(a[r][s]));

  float rowacc[4][4];
  #pragma unroll
  for (int r = 0; r < 4; ++r)
    #pragma unroll
    for (int i = 0; i < 4; ++i) rowacc[r][i] = 0.0f;

  // Per-thread staging chunks: i0 = tid, i1 = tid+256 (chunk index 0..511).
  // chunk i -> c=i>>8, s=(i>>6)&3, l15=i&15, lq=(i>>4)&3; LDS dest = i*16B.
  int i0 = tid, i1 = tid + 256;
  int c0 = i0 >> 8, s0 = (i0 >> 6) & 3, f0 = i0 & 15, q0 = (i0 >> 4) & 3;
  int c1 = i1 >> 8, s1 = (i1 >> 6) & 3, f1 = i1 & 15, q1 = (i1 >> 4) & 3;
  const short* ga = H + (size_t)(colbase + c0 * 16 + f0) * DIM + s0 * 32 + q0 * 8;
  const short* gb = H + (size_t)(colbase + c1 * 16 + f1) * DIM + s1 * 32 + q1 * 8;

  // Prologue: stage tile 0 into buffer 0.
  async_copy16(ga, (void*)&smem[i0 * 8]);
  async_copy16(gb, (void*)&smem[i1 * 8]);
  __syncthreads();

  int buf = 0;
  for (int ct = 0; ct < NT; ++ct) {
    // Prefetch tile ct+1 into the other buffer (in flight during compute).
    if (ct + 1 < NT) {
      ga += CT * DIM;
      gb += CT * DIM;
      int d = (buf ^ 1) * 4096;
      async_copy16(ga, (void*)&smem[d + i0 * 8]);
      async_copy16(gb, (void*)&smem[d + i1 * 8]);
    }

    const short* bsrc = &smem[buf * 4096];
    #pragma unroll
    for (int c = 0; c < 2; ++c) {
      short8 b[4];
      #pragma unroll
      for (int s = 0; s < 4; ++s)
        b[s] = *(const short8*)&bsrc[(c * 256 + s * 64 + lane) * 8];
      #pragma unroll
      for (int r = 0; r < 4; ++r) {
        float4v acc = {0.f, 0.f, 0.f, 0.f};
        #pragma unroll
        for (int s = 0; s < 4; ++s)
          acc = __builtin_amdgcn_mfma_f32_16x16x32_bf16(a[r][s], b[s], acc, 0, 0, 0);
        #pragma unroll
        for (int i = 0; i < 4; ++i)
          rowacc[r][i] += fast_exp2(acc[i]);   // acc already = 2*log2e*dot
      }
    }
    // One barrier per tile: drains this wave's vmcnt (prefetch done, covered
    // by the compute above) and lgkm, then syncs so buffers can swap.
    __syncthreads();
    buf ^= 1;
  }

  // Reduce across the 16 column-lanes (lane&15) holding the same rows.
  #pragma unroll
  for (int r = 0; r < 4; ++r)
    #pragma unroll
    for (int i = 0; i < 4; ++i) {
      float v = rowacc[r][i];
      v += __shfl_xor(v, 1);
      v += __shfl_xor(v, 2);
      v += __shfl_xor(v, 4);
      v += __shfl_xor(v, 8);
      rowacc[r][i] = v;
    }
  if (m == 0) {
    #pragma unroll
    for (int r = 0; r < 4; ++r)
      #pragma unroll
      for (int i = 0; i < 4; ++i)
        atomicAdd(&rowsum[rowbase + r * 16 + q * 4 + i], rowacc[r][i]);
  }
}

// ---------------------------------------------------------------------------
// Kernel 3: loss = ( sum_i log(rowsum_i - e^2) - 4 * sum_i posdot_i ) / 2N
// ---------------------------------------------------------------------------
__global__ __launch_bounds__(1024) void finalize(
    const float* __restrict__ rowsum, const float* __restrict__ posdot,
    float* __restrict__ out) {
  __shared__ float red[32];
  int tid = threadIdx.x;
  float ld = 0.0f, pp = 0.0f;
  for (int i = tid; i < TWO_N; i += 1024) ld += logf(rowsum[i] - EXP_TWO);
  for (int i = tid; i < N_ROWS; i += 1024) pp += posdot[i];
  #pragma unroll
  for (int m = 32; m; m >>= 1) {
    ld += __shfl_xor(ld, m);
    pp += __shfl_xor(pp, m);
  }
  if ((tid & 63) == 0) {
    red[tid >> 6] = ld;
    red[16 + (tid >> 6)] = pp;
  }
  __syncthreads();
  if (tid == 0) {
    float tl = 0.0f, tp = 0.0f;
    #pragma unroll
    for (int i = 0; i < 16; ++i) { tl += red[i]; tp += red[16 + i]; }
    *out = (tl - 4.0f * tp) / (float)TWO_N;
  }
}

extern "C" void kernel_launch(void* const* d_in, const int* in_sizes, int n_in,
                              void* d_out, int out_size, void* d_ws, size_t ws_size,
                              hipStream_t stream) {
  const float* h1 = (const float*)d_in[0];
  const float* h2 = (const float*)d_in[1];
  char* ws = (char*)d_ws;

  __hip_bfloat16* Hb = (__hip_bfloat16*)ws;                       // 4 MB
  float* rowsum      = (float*)(ws + 4194304);                    // 64 KB
  float* posdot      = (float*)(ws + 4194304 + 65536);            // 32 KB
  float* out         = (float*)d_out;

  norm_kernel<<<N_ROWS / 4, 256, 0, stream>>>(h1, h2, Hb, posdot, rowsum);
  ntx_main<<<dim3(TWO_N / 256, CSPLIT), 256, 0, stream>>>(Hb, rowsum);
  finalize<<<1, 1024, 0, stream>>>(rowsum, posdot, out);
}

// Round 3
// 132.567 us; speedup vs baseline: 1.3617x; 1.0244x over previous
//
#include <hip/hip_runtime.h>
#include <hip/hip_bf16.h>

#define N_ROWS 8192
#define DIM    128
#define TWO_N  16384
#define NBLK   64                         // 256-row/col block stripes
#define NTRI   (NBLK * (NBLK + 1) / 2)    // 2080 triangular blocks
#define CT     32                         // cols per LDS tile
#define NT_SQ  8                          // 256 cols per block / CT
#define EXP_TWO 7.38905609893065f
// sqrt(2 * log2(e)): folding exp(2*dot) == exp2(SCALE^2 * dot) into the operands
#define H_SCALE 1.6986436f

typedef __attribute__((ext_vector_type(8))) short short8;
typedef __attribute__((ext_vector_type(4))) float float4v;

__device__ inline void async_copy16(const void* g, void* l) {
  __builtin_amdgcn_global_load_lds(
      (const __attribute__((address_space(1))) void*)g,
      (__attribute__((address_space(3))) void*)l, 16, 0, 0);
}

__device__ inline float fast_exp2(float x) {
#if __has_builtin(__builtin_amdgcn_exp2f)
  return __builtin_amdgcn_exp2f(x);
#else
  return exp2f(x);
#endif
}

// ---------------------------------------------------------------------------
// Kernel 1: L2-normalize rows of h1,h2 (fp32), write bf16 H = [h1n; h2n]
// scaled by sqrt(2*log2 e) so the GEMM accumulator is already the exp2 arg.
// Also writes exact fp32 pos-dot per row (unscaled) and zeroes rowsum.
// One wave per row; block = 4 waves.
// ---------------------------------------------------------------------------
__global__ __launch_bounds__(256) void norm_kernel(
    const float* __restrict__ h1, const float* __restrict__ h2,
    __hip_bfloat16* __restrict__ Hb, float* __restrict__ posdot,
    float* __restrict__ rowsum) {
  // zero rowsum[16384]: 2048 blocks x 8 entries
  if (threadIdx.x < 8) rowsum[blockIdx.x * 8 + threadIdx.x] = 0.0f;

  int lane = threadIdx.x & 63;
  int w    = threadIdx.x >> 6;
  int row  = blockIdx.x * 4 + w;                  // 0..8191

  const float2* p1 = (const float2*)(h1 + (size_t)row * DIM);
  const float2* p2 = (const float2*)(h2 + (size_t)row * DIM);
  float2 v1 = p1[lane];
  float2 v2 = p2[lane];

  float ss1 = v1.x * v1.x + v1.y * v1.y;
  float ss2 = v2.x * v2.x + v2.y * v2.y;
  #pragma unroll
  for (int m = 32; m; m >>= 1) {
    ss1 += __shfl_xor(ss1, m);
    ss2 += __shfl_xor(ss2, m);
  }
  float inv1 = 1.0f / fmaxf(sqrtf(ss1), 1e-12f);
  float inv2 = 1.0f / fmaxf(sqrtf(ss2), 1e-12f);

  float ax = v1.x * inv1, ay = v1.y * inv1;
  float bx = v2.x * inv2, by = v2.y * inv2;

  float pd = ax * bx + ay * by;       // exact fp32 posdot (unscaled)
  #pragma unroll
  for (int m = 32; m; m >>= 1) pd += __shfl_xor(pd, m);

  __hip_bfloat162* o1 = (__hip_bfloat162*)(Hb + (size_t)row * DIM);
  __hip_bfloat162* o2 = (__hip_bfloat162*)(Hb + (size_t)(row + N_ROWS) * DIM);
  __hip_bfloat162 t1, t2;
  t1.x = __float2bfloat16(ax * H_SCALE); t1.y = __float2bfloat16(ay * H_SCALE);
  t2.x = __float2bfloat16(bx * H_SCALE); t2.y = __float2bfloat16(by * H_SCALE);
  o1[lane] = t1;
  o2[lane] = t2;

  if (lane == 0) posdot[row] = pd;
}

// ---------------------------------------------------------------------------
// Kernel 2: row sums of exp2(H H^T), exploiting SYMMETRY: only the upper
// block-triangle (J >= I) of the 64x64 grid of 256x256 tiles is computed.
// Off-diagonal blocks reduce each exp tile along BOTH fragment axes:
//   - across lane&15 (cols)        -> row sums for stripe I (registers)
//   - across regs i,r and lane>>4  -> col sums for stripe J (LDS slices)
// Diagonal blocks do row sums only (their square covers both triangles).
// Block: 256 threads = 4 waves; each wave owns 64 rows, A pinned in regs.
// B tiles (32 cols x 128 k) double-buffered in LDS via global_load_lds in
// MFMA fragment order; single __syncthreads per tile.
// ---------------------------------------------------------------------------
__global__ __launch_bounds__(256, 2) void ntx_main(
    const __hip_bfloat16* __restrict__ Hb, float* __restrict__ rowsum) {
  __shared__ short smem[2 * 4096];    // 16 KB: double-buffered B tiles
  __shared__ float colacc[4][256];    // 4 KB: per-wave col-sum slices
  const short* H = (const short*)Hb;

  int tid  = threadIdx.x;
  int lane = tid & 63;
  int w    = tid >> 6;
  int q    = lane >> 4;     // k-chunk selector within fragment
  int m    = lane & 15;     // row-within-subtile / col-within-subtile

  // Triangular decode: blockIdx.x -> (I, J) with J >= I over NBLK stripes.
  // C(I) = I*(2*NBLK+1-I)/2 blocks precede stripe I.
  int t = blockIdx.x;
  int I = (int)((129.0f - sqrtf(129.0f * 129.0f - 8.0f * (float)t)) * 0.5f);
  while ((I + 1) * (129 - (I + 1)) / 2 <= t) ++I;   // fixup fp rounding
  while (I * (129 - I) / 2 > t) --I;
  int J = I + (t - I * (129 - I) / 2);
  bool diag = (I == J);

  int rowbase = I * 256 + w * 64;
  int colbase = J * 256;

  // A fragments: 4 row-subtiles x 4 k-steps, held for the whole kernel.
  short8 a[4][4];
  #pragma unroll
  for (int r = 0; r < 4; ++r)
    #pragma unroll
    for (int s = 0; s < 4; ++s)
      a[r][s] = *(const short8*)(H + (size_t)(rowbase + r * 16 + m) * DIM + s * 32 + q * 8);
  // Pin A in registers: opaque volatile asm forbids remat/reload in the loop.
  #pragma unroll
  for (int r = 0; r < 4; ++r)
    #pragma unroll
    for (int s = 0; s < 4; ++s)
      asm volatile("" : "+v"(a[r][s]));

  float rowacc[4][4];
  #pragma unroll
  for (int r = 0; r < 4; ++r)
    #pragma unroll
    for (int i = 0; i < 4; ++i) rowacc[r][i] = 0.0f;

  // Per-thread staging chunks: i0 = tid, i1 = tid+256 (chunk index 0..511).
  // chunk i -> c=i>>8, s=(i>>6)&3, l15=i&15, lq=(i>>4)&3; LDS dest = i*16B.
  int i0 = tid, i1 = tid + 256;
  int c0 = i0 >> 8, s0 = (i0 >> 6) & 3, f0 = i0 & 15, q0 = (i0 >> 4) & 3;
  int c1 = i1 >> 8, s1 = (i1 >> 6) & 3, f1 = i1 & 15, q1 = (i1 >> 4) & 3;
  const short* ga = H + (size_t)(colbase + c0 * 16 + f0) * DIM + s0 * 32 + q0 * 8;
  const short* gb = H + (size_t)(colbase + c1 * 16 + f1) * DIM + s1 * 32 + q1 * 8;

  // Prologue: stage tile 0 into buffer 0.
  async_copy16(ga, (void*)&smem[i0 * 8]);
  async_copy16(gb, (void*)&smem[i1 * 8]);
  __syncthreads();

  int buf = 0;
  for (int ct = 0; ct < NT_SQ; ++ct) {
    // Prefetch tile ct+1 into the other buffer (in flight during compute).
    if (ct + 1 < NT_SQ) {
      ga += CT * DIM;
      gb += CT * DIM;
      int d = (buf ^ 1) * 4096;
      async_copy16(ga, (void*)&smem[d + i0 * 8]);
      async_copy16(gb, (void*)&smem[d + i1 * 8]);
    }

    const short* bsrc = &smem[buf * 4096];
    #pragma unroll
    for (int c = 0; c < 2; ++c) {
      short8 b[4];
      #pragma unroll
      for (int s = 0; s < 4; ++s)
        b[s] = *(const short8*)&bsrc[(c * 256 + s * 64 + lane) * 8];
      float cp = 0.0f;   // col partial: this lane's col (c*16+m), wave's rows
      #pragma unroll
      for (int r = 0; r < 4; ++r) {
        float4v acc = {0.f, 0.f, 0.f, 0.f};
        #pragma unroll
        for (int s = 0; s < 4; ++s)
          acc = __builtin_amdgcn_mfma_f32_16x16x32_bf16(a[r][s], b[s], acc, 0, 0, 0);
        #pragma unroll
        for (int i = 0; i < 4; ++i) {
          float e = fast_exp2(acc[i]);   // acc already = 2*log2e*dot
          rowacc[r][i] += e;
          cp += e;
        }
      }
      if (!diag) {
        // reduce over the 4 q-groups (rows): all lanes then hold the
        // col sum over this wave's 64 rows for col c*16+m.
        cp += __shfl_xor(cp, 16);
        cp += __shfl_xor(cp, 32);
        if (q == 0) colacc[w][ct * 32 + c * 16 + m] = cp;
      }
    }
    // One barrier per tile: prefetch (issued pre-compute) drains here,
    // covered by the compute above; syncs buffer swap.
    __syncthreads();
    buf ^= 1;
  }

  // Row sums: reduce across the 16 column-lanes holding the same rows.
  #pragma unroll
  for (int r = 0; r < 4; ++r)
    #pragma unroll
    for (int i = 0; i < 4; ++i) {
      float v = rowacc[r][i];
      v += __shfl_xor(v, 1);
      v += __shfl_xor(v, 2);
      v += __shfl_xor(v, 4);
      v += __shfl_xor(v, 8);
      rowacc[r][i] = v;
    }
  if (m == 0) {
    #pragma unroll
    for (int r = 0; r < 4; ++r)
      #pragma unroll
      for (int i = 0; i < 4; ++i)
        atomicAdd(&rowsum[rowbase + r * 16 + q * 4 + i], rowacc[r][i]);
  }

  // Col sums -> stripe J (symmetric contribution). colacc writes were all
  // before the loop's final __syncthreads, so they are visible here.
  if (!diag) {
    float v = colacc[0][tid] + colacc[1][tid] + colacc[2][tid] + colacc[3][tid];
    atomicAdd(&rowsum[colbase + tid], v);
  }
}

// ---------------------------------------------------------------------------
// Kernel 3: loss = ( sum_i log(rowsum_i - e^2) - 4 * sum_i posdot_i ) / 2N
// ---------------------------------------------------------------------------
__global__ __launch_bounds__(1024) void finalize(
    const float* __restrict__ rowsum, const float* __restrict__ posdot,
    float* __restrict__ out) {
  __shared__ float red[32];
  int tid = threadIdx.x;
  float ld = 0.0f, pp = 0.0f;
  for (int i = tid; i < TWO_N; i += 1024) ld += logf(rowsum[i] - EXP_TWO);
  for (int i = tid; i < N_ROWS; i += 1024) pp += posdot[i];
  #pragma unroll
  for (int m = 32; m; m >>= 1) {
    ld += __shfl_xor(ld, m);
    pp += __shfl_xor(pp, m);
  }
  if ((tid & 63) == 0) {
    red[tid >> 6] = ld;
    red[16 + (tid >> 6)] = pp;
  }
  __syncthreads();
  if (tid == 0) {
    float tl = 0.0f, tp = 0.0f;
    #pragma unroll
    for (int i = 0; i < 16; ++i) { tl += red[i]; tp += red[16 + i]; }
    *out = (tl - 4.0f * tp) / (float)TWO_N;
  }
}

extern "C" void kernel_launch(void* const* d_in, const int* in_sizes, int n_in,
                              void* d_out, int out_size, void* d_ws, size_t ws_size,
                              hipStream_t stream) {
  const float* h1 = (const float*)d_in[0];
  const float* h2 = (const float*)d_in[1];
  char* ws = (char*)d_ws;

  __hip_bfloat16* Hb = (__hip_bfloat16*)ws;                       // 4 MB
  float* rowsum      = (float*)(ws + 4194304);                    // 64 KB
  float* posdot      = (float*)(ws + 4194304 + 65536);            // 32 KB
  float* out         = (float*)d_out;

  norm_kernel<<<N_ROWS / 4, 256, 0, stream>>>(h1, h2, Hb, posdot, rowsum);
  ntx_main<<<NTRI, 256, 0, stream>>>(Hb, rowsum);
  finalize<<<1, 1024, 0, stream>>>(rowsum, posdot, out);
}